// Round 2
// baseline (312.763 us; speedup 1.0000x reference)
//
#include <hip/hip_runtime.h>
#include <hip/hip_bf16.h>

#define N_NODES 262144
#define NUM_C   256
#define DIM     128
#define NUM_G   128
#define GMAX    8

typedef short  bf16x8 __attribute__((ext_vector_type(8)));
typedef float  f32x4  __attribute__((ext_vector_type(4)));

__device__ __forceinline__ short f2b(float f) {
    __hip_bfloat16 h = __float2bfloat16(f);
    return *reinterpret_cast<short*>(&h);
}

// ---------------------------------------------------------------------------
// Prep: zero out, convert W fp32->bf16, compute c_sq (fp32), build cum_end[g]
// (cumulative node count through graph g) from the sorted batch array.
// Grid: 128 blocks x 256 threads.  (verified round 1)
// ---------------------------------------------------------------------------
__global__ void centroid_prep(const float* __restrict__ W,
                              const int* __restrict__ batch,
                              float* __restrict__ out,
                              short* __restrict__ Wb,
                              float* __restrict__ csq,
                              int* __restrict__ cum_end)
{
    const int t   = threadIdx.x;
    const int b   = blockIdx.x;
    const int gid = b * 256 + t;

    float w = W[gid];
    out[gid] = 0.f;
    Wb[gid] = f2b(w);

    __shared__ float red[256];
    red[t] = w * w;
    __syncthreads();
    for (int off = 64; off > 0; off >>= 1) {
        if ((t & 127) < off) red[t] += red[t + off];
        __syncthreads();
    }
    if (t == 0)   csq[2 * b]     = red[0];
    if (t == 128) csq[2 * b + 1] = red[128];

    long i0 = (long)gid * 8;
    int g = batch[i0];
    if (gid == 0) {
        for (int gg = 0; gg < g; ++gg) cum_end[gg] = 0;
    }
    for (int k = 0; k < 8; ++k) {
        long i = i0 + k;
        int gn = (i + 1 < N_NODES) ? batch[i + 1] : NUM_G;
        if (gn != g) {
            for (int gg = g; gg < gn; ++gg) cum_end[gg] = (int)(i + 1);
        }
        g = gn;
    }
}

// ---------------------------------------------------------------------------
// Main (restructured): 2048 blocks x 512 threads; wave = 16 nodes x all 256
// centroids. Persistent per-wave state is only 4 bf16x8 A-fragments (16 VGPR)
// + 4 xsq floats; B-fragments stream from L1/L2-resident bf16 Wb (64 KB) in
// the 16-iteration column-tile loop. dist = sqrt(max(xsq+csq-2*cross,0));
// pooled via wave butterfly -> block LDS accumulator -> global atomics.
// ---------------------------------------------------------------------------
__global__ __launch_bounds__(512, 4) void centroid_main(
    const float* __restrict__ x,
    const int* __restrict__ batch,
    const short* __restrict__ Wb,
    const float* __restrict__ csq,
    float* __restrict__ out)
{
    __shared__ float lacc[GMAX * NUM_C];
    const int t  = threadIdx.x;
    const int nb = blockIdx.x << 7;   // 128 nodes per block

    for (int i = t; i < GMAX * NUM_C; i += 512) lacc[i] = 0.f;
    __syncthreads();

    const int  gmin    = batch[nb];
    const int  span    = batch[nb + 127] - gmin + 1;
    const bool use_lds = (span <= GMAX);

    const int lane = t & 63;
    const int m16  = lane & 15;
    const int quad = lane >> 4;
    const int n0   = nb + (t >> 6) * 16;   // this wave's 16 nodes

    // ---- A fragments (16 VGPRs, persistent) + row sum-of-squares (fp32) ----
    bf16x8 a[4];
    float  ss = 0.f;
    const float* xp = x + (long)(n0 + m16) * DIM + quad * 8;
#pragma unroll
    for (int ks = 0; ks < 4; ++ks) {
        f32x4 u0 = *(const f32x4*)(xp + ks * 32);
        f32x4 u1 = *(const f32x4*)(xp + ks * 32 + 4);
        bf16x8 av;
#pragma unroll
        for (int j = 0; j < 4; ++j) {
            ss += u0[j] * u0[j] + u1[j] * u1[j];
            av[j]     = f2b(u0[j]);
            av[j + 4] = f2b(u1[j]);
        }
        a[ks] = av;
    }
    ss += __shfl_xor(ss, 16);
    ss += __shfl_xor(ss, 32);          // lane now has xsq of node (n0 + m16)
    float pre[4];                       // xsq in D-layout rows (quad*4 + r)
#pragma unroll
    for (int r = 0; r < 4; ++r) pre[r] = __shfl(ss, quad * 4 + r);

    const int  g0  = batch[n0];
    const bool uni = (g0 == batch[n0 + 15]);
    int grow[4];
    if (!uni) {
#pragma unroll
        for (int r = 0; r < 4; ++r) grow[r] = batch[n0 + quad * 4 + r];
    }

    // ---- column-tile loop: stream B from cache ----
#pragma unroll 2
    for (int ct = 0; ct < 16; ++ct) {
        const int c = ct * 16 + m16;
        const short* wp = Wb + c * DIM + quad * 8;
        bf16x8 b0 = *(const bf16x8*)(wp);
        bf16x8 b1 = *(const bf16x8*)(wp + 32);
        bf16x8 b2 = *(const bf16x8*)(wp + 64);
        bf16x8 b3 = *(const bf16x8*)(wp + 96);
        const float cs = csq[c];

        f32x4 acc = {0.f, 0.f, 0.f, 0.f};
        acc = __builtin_amdgcn_mfma_f32_16x16x32_bf16(a[0], b0, acc, 0, 0, 0);
        acc = __builtin_amdgcn_mfma_f32_16x16x32_bf16(a[1], b1, acc, 0, 0, 0);
        acc = __builtin_amdgcn_mfma_f32_16x16x32_bf16(a[2], b2, acc, 0, 0, 0);
        acc = __builtin_amdgcn_mfma_f32_16x16x32_bf16(a[3], b3, acc, 0, 0, 0);

        if (use_lds && uni) {
            float v = 0.f;
#pragma unroll
            for (int r = 0; r < 4; ++r) {
                float d2 = (pre[r] + cs) - 2.f * acc[r];
                v += sqrtf(fmaxf(d2, 0.f));
            }
            v += __shfl_xor(v, 16);
            v += __shfl_xor(v, 32);
            if (quad == 0)
                atomicAdd(&lacc[(g0 - gmin) * NUM_C + c], v);
        } else {
#pragma unroll
            for (int r = 0; r < 4; ++r) {
                float d2 = (pre[r] + cs) - 2.f * acc[r];
                float d  = sqrtf(fmaxf(d2, 0.f));
                int   g  = uni ? g0 : grow[r];
                if (use_lds) atomicAdd(&lacc[(g - gmin) * NUM_C + c], d);
                else         atomicAdd(&out[g * NUM_C + c], d);
            }
        }
    }

    __syncthreads();
    if (use_lds) {
        for (int i = t; i < span * NUM_C; i += 512)
            atomicAdd(&out[(gmin + (i >> 8)) * NUM_C + (i & 255)], lacc[i]);
    }
}

// ---------------------------------------------------------------------------
// Finish: divide sums by per-graph counts. Grid: 128 blocks x 256 threads.
// ---------------------------------------------------------------------------
__global__ void centroid_finish(float* __restrict__ out,
                                const int* __restrict__ cum_end)
{
    const int g = blockIdx.x;
    const int c = threadIdx.x;
    int cnt = cum_end[g] - (g ? cum_end[g - 1] : 0);
    float denom = (float)(cnt > 0 ? cnt : 1);
    out[g * NUM_C + c] /= denom;
}

extern "C" void kernel_launch(void* const* d_in, const int* in_sizes, int n_in,
                              void* d_out, int out_size, void* d_ws, size_t ws_size,
                              hipStream_t stream) {
    const float* x     = (const float*)d_in[0];
    const int*   batch = (const int*)d_in[1];
    const float* W     = (const float*)d_in[2];
    float*       out   = (float*)d_out;

    // workspace: Wb (64 KB) | csq (1 KB) | cum_end (512 B)
    short* Wb      = (short*)d_ws;
    float* csq     = (float*)((char*)d_ws + 65536);
    int*   cum_end = (int*)((char*)d_ws + 65536 + 1024);

    centroid_prep<<<128, 256, 0, stream>>>(W, batch, out, Wb, csq, cum_end);
    centroid_main<<<N_NODES / 128, 512, 0, stream>>>(x, batch, Wb, csq, out);
    centroid_finish<<<NUM_G, 256, 0, stream>>>(out, cum_end);
}

// Round 3
// 228.427 us; speedup vs baseline: 1.3692x; 1.3692x over previous
//
#include <hip/hip_runtime.h>
#include <hip/hip_bf16.h>

#define N_NODES 262144
#define NUM_C   256
#define DIM     128
#define NUM_G   128
#define GMAX    8
#define WPAD    136   // padded LDS row stride in shorts (272 B, 16B-aligned)

typedef short  bf16x8 __attribute__((ext_vector_type(8)));
typedef float  f32x4  __attribute__((ext_vector_type(4)));

__device__ __forceinline__ short f2b(float f) {
    __hip_bfloat16 h = __float2bfloat16(f);
    return *reinterpret_cast<short*>(&h);
}

// ---------------------------------------------------------------------------
// Prep: zero out, convert W fp32->bf16 (row-major, unpadded), compute c_sq,
// build cum_end[g] from the sorted batch. Grid: 128 x 256. (verified r1/r2)
// ---------------------------------------------------------------------------
__global__ void centroid_prep(const float* __restrict__ W,
                              const int* __restrict__ batch,
                              float* __restrict__ out,
                              short* __restrict__ Wb,
                              float* __restrict__ csq,
                              int* __restrict__ cum_end)
{
    const int t   = threadIdx.x;
    const int b   = blockIdx.x;
    const int gid = b * 256 + t;

    float w = W[gid];
    out[gid] = 0.f;
    Wb[gid] = f2b(w);

    __shared__ float red[256];
    red[t] = w * w;
    __syncthreads();
    for (int off = 64; off > 0; off >>= 1) {
        if ((t & 127) < off) red[t] += red[t + off];
        __syncthreads();
    }
    if (t == 0)   csq[2 * b]     = red[0];
    if (t == 128) csq[2 * b + 1] = red[128];

    long i0 = (long)gid * 8;
    int g = batch[i0];
    if (gid == 0) {
        for (int gg = 0; gg < g; ++gg) cum_end[gg] = 0;
    }
    for (int k = 0; k < 8; ++k) {
        long i = i0 + k;
        int gn = (i + 1 < N_NODES) ? batch[i + 1] : NUM_G;
        if (gn != g) {
            for (int gg = g; gg < gn; ++gg) cum_end[gg] = (int)(i + 1);
        }
        g = gn;
    }
}

// ---------------------------------------------------------------------------
// Main: 1024 blocks x 512 threads. Block = 256 nodes; wave = 32 nodes
// (2 subtiles of 16). Whole bf16 W staged in LDS (padded stride -> <=2-way
// bank aliasing); A-fragments persistent in VGPRs; 8 MFMAs per B-set.
// dist = sqrt(max(xsq + csq - 2*cross, 0)); pooled via wave butterfly ->
// block LDS accumulator -> global atomics; finish divides by counts.
// ---------------------------------------------------------------------------
__global__ __launch_bounds__(512, 4) void centroid_main(
    const float* __restrict__ x,
    const int* __restrict__ batch,
    const short* __restrict__ Wb,
    const float* __restrict__ csq,
    float* __restrict__ out)
{
    __shared__ short wlds[NUM_C * WPAD];      // 69632 B
    __shared__ float lacc[GMAX * NUM_C];      //  8192 B
    __shared__ float csq_l[NUM_C];            //  1024 B

    const int t  = threadIdx.x;
    const int nb = blockIdx.x << 8;           // 256 nodes per block

    // ---- stage W (bf16) into padded LDS, coalesced global reads ----
#pragma unroll
    for (int i = 0; i < 8; ++i) {
        int k = i * 512 + t;                  // chunk of 8 shorts, 4096 total
        bf16x8 v = *(const bf16x8*)(Wb + k * 8);
        *(bf16x8*)(wlds + (k >> 4) * WPAD + (k & 15) * 8) = v;
    }
    if (t < NUM_C) csq_l[t] = csq[t];
#pragma unroll
    for (int i = t; i < GMAX * NUM_C; i += 512) lacc[i] = 0.f;

    const int  gmin    = batch[nb];
    const int  span    = batch[nb + 255] - gmin + 1;
    const bool use_lds = (span <= GMAX);

    const int lane = t & 63;
    const int m16  = lane & 15;
    const int quad = lane >> 4;
    const int n0   = nb + (t >> 6) * 32;      // wave's 32 nodes

    // ---- A fragments (32 VGPRs) + row sum-of-squares ----
    bf16x8 a[2][4];
    float  pre[2][4];
    int    g0[2];
    bool   uni[2];
    int    grow[2][4];
#pragma unroll
    for (int s = 0; s < 2; ++s) {
        const float* xp = x + (long)(n0 + s * 16 + m16) * DIM + quad * 8;
        float ss = 0.f;
#pragma unroll
        for (int ks = 0; ks < 4; ++ks) {
            f32x4 u0 = *(const f32x4*)(xp + ks * 32);
            f32x4 u1 = *(const f32x4*)(xp + ks * 32 + 4);
            bf16x8 av;
#pragma unroll
            for (int j = 0; j < 4; ++j) {
                ss += u0[j] * u0[j] + u1[j] * u1[j];
                av[j]     = f2b(u0[j]);
                av[j + 4] = f2b(u1[j]);
            }
            a[s][ks] = av;
        }
        ss += __shfl_xor(ss, 16);
        ss += __shfl_xor(ss, 32);
#pragma unroll
        for (int r = 0; r < 4; ++r) pre[s][r] = __shfl(ss, quad * 4 + r);

        g0[s]  = batch[n0 + s * 16];
        uni[s] = (g0[s] == batch[n0 + s * 16 + 15]);
        if (!uni[s]) {
#pragma unroll
            for (int r = 0; r < 4; ++r) grow[s][r] = batch[n0 + s * 16 + quad * 4 + r];
        }
    }

    __syncthreads();   // W staging visible

    // ---- column-tile loop: B from LDS ----
#pragma unroll 2
    for (int ct = 0; ct < 16; ++ct) {
        const int c = ct * 16 + m16;
        const short* wp = wlds + c * WPAD + quad * 8;
        bf16x8 b0 = *(const bf16x8*)(wp);
        bf16x8 b1 = *(const bf16x8*)(wp + 32);
        bf16x8 b2 = *(const bf16x8*)(wp + 64);
        bf16x8 b3 = *(const bf16x8*)(wp + 96);
        const float cs = csq_l[c];

#pragma unroll
        for (int s = 0; s < 2; ++s) {
            f32x4 acc = {0.f, 0.f, 0.f, 0.f};
            acc = __builtin_amdgcn_mfma_f32_16x16x32_bf16(a[s][0], b0, acc, 0, 0, 0);
            acc = __builtin_amdgcn_mfma_f32_16x16x32_bf16(a[s][1], b1, acc, 0, 0, 0);
            acc = __builtin_amdgcn_mfma_f32_16x16x32_bf16(a[s][2], b2, acc, 0, 0, 0);
            acc = __builtin_amdgcn_mfma_f32_16x16x32_bf16(a[s][3], b3, acc, 0, 0, 0);

            if (use_lds && uni[s]) {
                float v = 0.f;
#pragma unroll
                for (int r = 0; r < 4; ++r) {
                    float d2 = __builtin_fmaf(acc[r], -2.f, pre[s][r] + cs);
                    v += __builtin_amdgcn_sqrtf(__builtin_fmaxf(d2, 0.f));
                }
                v += __shfl_xor(v, 16);
                v += __shfl_xor(v, 32);
                if (quad == 0)
                    atomicAdd(&lacc[(g0[s] - gmin) * NUM_C + c], v);
            } else {
#pragma unroll
                for (int r = 0; r < 4; ++r) {
                    float d2 = __builtin_fmaf(acc[r], -2.f, pre[s][r] + cs);
                    float d  = __builtin_amdgcn_sqrtf(__builtin_fmaxf(d2, 0.f));
                    int   g  = uni[s] ? g0[s] : grow[s][r];
                    if (use_lds) atomicAdd(&lacc[(g - gmin) * NUM_C + c], d);
                    else         atomicAdd(&out[g * NUM_C + c], d);
                }
            }
        }
    }

    __syncthreads();
    if (use_lds) {
        for (int i = t; i < span * NUM_C; i += 512)
            atomicAdd(&out[(gmin + (i >> 8)) * NUM_C + (i & 255)], lacc[i]);
    }
}

// ---------------------------------------------------------------------------
// Finish: divide sums by per-graph counts. Grid: 128 x 256.
// ---------------------------------------------------------------------------
__global__ void centroid_finish(float* __restrict__ out,
                                const int* __restrict__ cum_end)
{
    const int g = blockIdx.x;
    const int c = threadIdx.x;
    int cnt = cum_end[g] - (g ? cum_end[g - 1] : 0);
    float denom = (float)(cnt > 0 ? cnt : 1);
    out[g * NUM_C + c] /= denom;
}

extern "C" void kernel_launch(void* const* d_in, const int* in_sizes, int n_in,
                              void* d_out, int out_size, void* d_ws, size_t ws_size,
                              hipStream_t stream) {
    const float* x     = (const float*)d_in[0];
    const int*   batch = (const int*)d_in[1];
    const float* W     = (const float*)d_in[2];
    float*       out   = (float*)d_out;

    // workspace: Wb (64 KB) | csq (1 KB) | cum_end (512 B)
    short* Wb      = (short*)d_ws;
    float* csq     = (float*)((char*)d_ws + 65536);
    int*   cum_end = (int*)((char*)d_ws + 65536 + 1024);

    centroid_prep<<<128, 256, 0, stream>>>(W, batch, out, Wb, csq, cum_end);
    centroid_main<<<N_NODES / 256, 512, 0, stream>>>(x, batch, Wb, csq, out);
    centroid_finish<<<NUM_G, 256, 0, stream>>>(out, cum_end);
}